// Round 13
// baseline (38.855 us; speedup 1.0000x reference)
//
#include <hip/hip_runtime.h>
#include <hip/hip_bf16.h>

#define NBINS 20
#define TPB 256
#define K 4   // float4 loads per stream per thread per chunk

typedef float fvec4 __attribute__((ext_vector_type(4)));

// R13 = R12 with CACHED loads (single-variable A/B vs NT). Theory: per-CU
// outstanding-line limit makes read rate ~ lines*64B/latency; cached loads
// keep the 134 MB working set L3-resident (256 MB) across replays -> lower
// average latency -> higher throughput. Depth-3 static pipeline retained.
#define LOADSET(cv, av, base)                                                      \
    _Pragma("unroll") for (int k = 0; k < K; ++k)                                  \
        cv[k] = confs[(base) + k * TPB];                                           \
    _Pragma("unroll") for (int k = 0; k < K; ++k)                                  \
        av[k] = accs[(base) + k * TPB];

#define PROCSET(cv, av)                                                            \
    _Pragma("unroll") for (int k = 0; k < K; ++k) {                                \
        _Pragma("unroll") for (int j = 0; j < 4; ++j) {                            \
            float c1 = cv[k][j];                                                   \
            float a1 = av[k][j];                                                   \
            float ft = __builtin_ceilf((c1 - 0.5f) * 40.0f);                       \
            unsigned int bin = (unsigned int)((int)ft - 1);                        \
            if (bin < (unsigned int)NBINS) s[bin * TPB + t] += c1 - a1;            \
        }                                                                          \
    }

// Non-atomic LDS RMW s[bin][tid] (bank = tid%32, 2-way aliasing = free).
// bin = ceil((c-0.5)*40)-1 == searchsorted(side='left')-1 (absmax 0.0, r1-12).
__global__ __launch_bounds__(TPB, 4) void ece_accum(
        const fvec4* __restrict__ confs,
        const fvec4* __restrict__ accs,
        int n4,                        // n/4
        float* __restrict__ partials,  // [NBINS][nb]
        int nb) {
    __shared__ float s[NBINS * TPB];
    const int t = threadIdx.x;
#pragma unroll
    for (int k = 0; k < NBINS; ++k) s[k * TPB + t] = 0.0f;
    __syncthreads();

    const int chunk = K * TPB;           // 1024 float4s per block-chunk
    const int nIter = n4 / chunk;        // 4096 for N=16.7M
    const int g = gridDim.x;

    if (nIter == 4 * g) {
        // exactly 4 chunks/block: fully static depth-3 pipeline
        const int i0 = (blockIdx.x + 0 * g) * chunk + t;
        const int i1 = (blockIdx.x + 1 * g) * chunk + t;
        const int i2 = (blockIdx.x + 2 * g) * chunk + t;
        const int i3 = (blockIdx.x + 3 * g) * chunk + t;
        fvec4 c0[K], a0[K], c1v[K], a1v[K], c2[K], a2[K];
        LOADSET(c0, a0, i0)
        LOADSET(c1v, a1v, i1)
        LOADSET(c2, a2, i2)
        PROCSET(c0, a0)
        LOADSET(c0, a0, i3)   // reuse set 0 for the 4th chunk
        PROCSET(c1v, a1v)
        PROCSET(c2, a2)
        PROCSET(c0, a0)
    } else {
        // generic depth-2 fallback
        int it = blockIdx.x;
        fvec4 c[K], a[K];
        bool have = (it < nIter);
        if (have) {
            const int base = it * chunk + t;
            LOADSET(c, a, base)
        }
        while (have) {
            const int itn = it + g;
            const bool hn = (itn < nIter);
            fvec4 nc[K], na[K];
            if (hn) {
                const int nbase = itn * chunk + t;
                LOADSET(nc, na, nbase)
            }
            PROCSET(c, a)
            it = itn;
            have = hn;
#pragma unroll
            for (int k = 0; k < K; ++k) { c[k] = nc[k]; a[k] = na[k]; }
        }
    }

    // tail (n4 not multiple of chunk) — block 0 (empty for N=16.7M)
    if (blockIdx.x == 0) {
        for (int i = nIter * chunk + t; i < n4; i += TPB) {
            fvec4 c4 = confs[i];
            fvec4 a4 = accs[i];
#pragma unroll
            for (int j = 0; j < 4; ++j) {
                float c1 = c4[j];
                float a1 = a4[j];
                float ft = __builtin_ceilf((c1 - 0.5f) * 40.0f);
                unsigned int bin = (unsigned int)((int)ft - 1);
                if (bin < (unsigned int)NBINS)
                    s[bin * TPB + t] += c1 - a1;
            }
        }
    }
    __syncthreads();

    // block reduce, reusing s[]
    float v[NBINS];
#pragma unroll
    for (int b = 0; b < NBINS; ++b) v[b] = s[b * TPB + t];
#pragma unroll
    for (int b = 0; b < NBINS; ++b) {
#pragma unroll
        for (int m = 32; m >= 1; m >>= 1) v[b] += __shfl_xor(v[b], m, 64);
    }
    __syncthreads();
    const int wave = t >> 6, lane = t & 63;
    if (lane == 0) {
#pragma unroll
        for (int b = 0; b < NBINS; ++b) s[b * 4 + wave] = v[b];
    }
    __syncthreads();
    if (t < NBINS) {
        float sum = s[t * 4 + 0] + s[t * 4 + 1] + s[t * 4 + 2] + s[t * 4 + 3];
        partials[t * nb + blockIdx.x] = sum;
    }
}

// One block: reduce nb partials per bin, ece = sum_b |S_b| / N
__global__ __launch_bounds__(512) void ece_final(
        const float* __restrict__ partials,
        float* __restrict__ out,
        float inv_n, int nb) {
    float s[NBINS];
#pragma unroll
    for (int b = 0; b < NBINS; ++b) s[b] = 0.0f;

    const int tid = threadIdx.x;
    const int nb4 = nb >> 2;
#pragma unroll
    for (int b = 0; b < NBINS; ++b) {
        const fvec4* pb = (const fvec4*)(partials + b * nb);
        for (int k = tid; k < nb4; k += blockDim.x) {
            fvec4 v = pb[k];
            s[b] += (v[0] + v[1]) + (v[2] + v[3]);
        }
    }
#pragma unroll
    for (int b = 0; b < NBINS; ++b) {
#pragma unroll
        for (int m = 32; m >= 1; m >>= 1)
            s[b] += __shfl_xor(s[b], m, 64);
    }

    __shared__ float red[NBINS][8];
    const int wave = tid >> 6;
    const int lane = tid & 63;
    if (lane == 0) {
#pragma unroll
        for (int b = 0; b < NBINS; ++b) red[b][wave] = s[b];
    }
    __syncthreads();

    if (tid == 0) {
        float ece = 0.0f;
#pragma unroll
        for (int b = 0; b < NBINS; ++b) {
            float tt = 0.0f;
#pragma unroll
            for (int w = 0; w < 8; ++w) tt += red[b][w];
            ece += fabsf(tt);
        }
        out[0] = ece * inv_n;
    }
}

extern "C" void kernel_launch(void* const* d_in, const int* in_sizes, int n_in,
                              void* d_out, int out_size, void* d_ws, size_t ws_size,
                              hipStream_t stream) {
    const float* confs = (const float*)d_in[0];
    const float* accs = (const float*)d_in[1];
    const int n = in_sizes[0];   // 16,777,216
    const int n4 = n / 4;

    // 1024 blocks = 4/CU single-shot at (256,4); exactly 4 chunks/block
    int nb = 1024;
    int ws_cap = (int)(ws_size / (NBINS * sizeof(float)));
    ws_cap &= ~3;
    if (nb > ws_cap) nb = ws_cap;
    if (nb < 4) nb = 4;

    float* partials = (float*)d_ws;

    ece_accum<<<nb, TPB, 0, stream>>>((const fvec4*)confs, (const fvec4*)accs,
                                      n4, partials, nb);
    ece_final<<<1, 512, 0, stream>>>(partials, (float*)d_out, 1.0f / (float)n, nb);
}

// Round 14
// 35.975 us; speedup vs baseline: 1.0800x; 1.0800x over previous
//
#include <hip/hip_runtime.h>
#include <hip/hip_bf16.h>

#define NBINS 20
#define TPB 256
#define K 4   // float4 loads per stream per thread per chunk

typedef float fvec4 __attribute__((ext_vector_type(4)));

// R14 = R12 (NT loads + depth-3 static pipeline, best at 36.0 us) + LDS
// chain-split: element j updates s[j&1][bin][tid]. The parity index is a
// compile-time constant and the two 20KB halves are provably disjoint, so
// the compiler can interleave two independent 8-deep RMW chains instead of
// one 16-deep lgkmcnt-serialized chain. LDS 40KB -> 4 blocks/CU = 160 KiB
// exactly. bank = tid%32 (2-way aliasing = free).
// bin = ceil((c-0.5)*40)-1 == searchsorted(side='left')-1 (absmax 0.0, r1-13).
#define LOADSET(cv, av, base)                                                      \
    _Pragma("unroll") for (int k = 0; k < K; ++k)                                  \
        cv[k] = __builtin_nontemporal_load(&confs[(base) + k * TPB]);              \
    _Pragma("unroll") for (int k = 0; k < K; ++k)                                  \
        av[k] = __builtin_nontemporal_load(&accs[(base) + k * TPB]);

#define PROCSET(cv, av)                                                            \
    _Pragma("unroll") for (int k = 0; k < K; ++k) {                                \
        _Pragma("unroll") for (int j = 0; j < 4; ++j) {                            \
            float c1 = cv[k][j];                                                   \
            float a1 = av[k][j];                                                   \
            float ft = __builtin_ceilf((c1 - 0.5f) * 40.0f);                       \
            unsigned int bin = (unsigned int)((int)ft - 1);                        \
            if (bin < (unsigned int)NBINS)                                         \
                s[((j & 1) * NBINS + bin) * TPB + t] += c1 - a1;                   \
        }                                                                          \
    }

__global__ __launch_bounds__(TPB, 4) void ece_accum(
        const fvec4* __restrict__ confs,
        const fvec4* __restrict__ accs,
        int n4,                        // n/4
        float* __restrict__ partials,  // [NBINS][nb]
        int nb) {
    __shared__ float s[2 * NBINS * TPB];
    const int t = threadIdx.x;
#pragma unroll
    for (int k = 0; k < 2 * NBINS; ++k) s[k * TPB + t] = 0.0f;
    __syncthreads();

    const int chunk = K * TPB;           // 1024 float4s per block-chunk
    const int nIter = n4 / chunk;        // 4096 for N=16.7M
    const int g = gridDim.x;

    if (nIter == 4 * g) {
        // exactly 4 chunks/block: fully static depth-3 pipeline
        const int i0 = (blockIdx.x + 0 * g) * chunk + t;
        const int i1 = (blockIdx.x + 1 * g) * chunk + t;
        const int i2 = (blockIdx.x + 2 * g) * chunk + t;
        const int i3 = (blockIdx.x + 3 * g) * chunk + t;
        fvec4 c0[K], a0[K], c1v[K], a1v[K], c2[K], a2[K];
        LOADSET(c0, a0, i0)
        LOADSET(c1v, a1v, i1)
        LOADSET(c2, a2, i2)
        PROCSET(c0, a0)
        LOADSET(c0, a0, i3)   // reuse set 0 for the 4th chunk
        PROCSET(c1v, a1v)
        PROCSET(c2, a2)
        PROCSET(c0, a0)
    } else {
        // generic depth-2 fallback
        int it = blockIdx.x;
        fvec4 c[K], a[K];
        bool have = (it < nIter);
        if (have) {
            const int base = it * chunk + t;
            LOADSET(c, a, base)
        }
        while (have) {
            const int itn = it + g;
            const bool hn = (itn < nIter);
            fvec4 nc[K], na[K];
            if (hn) {
                const int nbase = itn * chunk + t;
                LOADSET(nc, na, nbase)
            }
            PROCSET(c, a)
            it = itn;
            have = hn;
#pragma unroll
            for (int k = 0; k < K; ++k) { c[k] = nc[k]; a[k] = na[k]; }
        }
    }

    // tail (n4 not multiple of chunk) — block 0 (empty for N=16.7M)
    if (blockIdx.x == 0) {
        for (int i = nIter * chunk + t; i < n4; i += TPB) {
            fvec4 c4 = confs[i];
            fvec4 a4 = accs[i];
#pragma unroll
            for (int j = 0; j < 4; ++j) {
                float c1 = c4[j];
                float a1 = a4[j];
                float ft = __builtin_ceilf((c1 - 0.5f) * 40.0f);
                unsigned int bin = (unsigned int)((int)ft - 1);
                if (bin < (unsigned int)NBINS)
                    s[((j & 1) * NBINS + bin) * TPB + t] += c1 - a1;
            }
        }
    }
    __syncthreads();

    // block reduce: sum both parity halves, then butterfly
    float v[NBINS];
#pragma unroll
    for (int b = 0; b < NBINS; ++b)
        v[b] = s[b * TPB + t] + s[(NBINS + b) * TPB + t];
#pragma unroll
    for (int b = 0; b < NBINS; ++b) {
#pragma unroll
        for (int m = 32; m >= 1; m >>= 1) v[b] += __shfl_xor(v[b], m, 64);
    }
    __syncthreads();
    const int wave = t >> 6, lane = t & 63;
    if (lane == 0) {
#pragma unroll
        for (int b = 0; b < NBINS; ++b) s[b * 4 + wave] = v[b];
    }
    __syncthreads();
    if (t < NBINS) {
        float sum = s[t * 4 + 0] + s[t * 4 + 1] + s[t * 4 + 2] + s[t * 4 + 3];
        partials[t * nb + blockIdx.x] = sum;
    }
}

// One block: reduce nb partials per bin, ece = sum_b |S_b| / N
__global__ __launch_bounds__(512) void ece_final(
        const float* __restrict__ partials,
        float* __restrict__ out,
        float inv_n, int nb) {
    float s[NBINS];
#pragma unroll
    for (int b = 0; b < NBINS; ++b) s[b] = 0.0f;

    const int tid = threadIdx.x;
    const int nb4 = nb >> 2;
#pragma unroll
    for (int b = 0; b < NBINS; ++b) {
        const fvec4* pb = (const fvec4*)(partials + b * nb);
        for (int k = tid; k < nb4; k += blockDim.x) {
            fvec4 v = pb[k];
            s[b] += (v[0] + v[1]) + (v[2] + v[3]);
        }
    }
#pragma unroll
    for (int b = 0; b < NBINS; ++b) {
#pragma unroll
        for (int m = 32; m >= 1; m >>= 1)
            s[b] += __shfl_xor(s[b], m, 64);
    }

    __shared__ float red[NBINS][8];
    const int wave = tid >> 6;
    const int lane = tid & 63;
    if (lane == 0) {
#pragma unroll
        for (int b = 0; b < NBINS; ++b) red[b][wave] = s[b];
    }
    __syncthreads();

    if (tid == 0) {
        float ece = 0.0f;
#pragma unroll
        for (int b = 0; b < NBINS; ++b) {
            float tt = 0.0f;
#pragma unroll
            for (int w = 0; w < 8; ++w) tt += red[b][w];
            ece += fabsf(tt);
        }
        out[0] = ece * inv_n;
    }
}

extern "C" void kernel_launch(void* const* d_in, const int* in_sizes, int n_in,
                              void* d_out, int out_size, void* d_ws, size_t ws_size,
                              hipStream_t stream) {
    const float* confs = (const float*)d_in[0];
    const float* accs = (const float*)d_in[1];
    const int n = in_sizes[0];   // 16,777,216
    const int n4 = n / 4;

    // 1024 blocks = 4/CU single-shot at (256,4) and 40KB LDS; 4 chunks/block
    int nb = 1024;
    int ws_cap = (int)(ws_size / (NBINS * sizeof(float)));
    ws_cap &= ~3;
    if (nb > ws_cap) nb = ws_cap;
    if (nb < 4) nb = 4;

    float* partials = (float*)d_ws;

    ece_accum<<<nb, TPB, 0, stream>>>((const fvec4*)confs, (const fvec4*)accs,
                                      n4, partials, nb);
    ece_final<<<1, 512, 0, stream>>>(partials, (float*)d_out, 1.0f / (float)n, nb);
}